// Round 6
// baseline (192.207 us; speedup 1.0000x reference)
//
#include <hip/hip_runtime.h>

typedef unsigned short u16;
typedef unsigned int u32;

#define NB 4
#define NN 512
#define ND 256
#define NH 256
#define TI 4

typedef __attribute__((ext_vector_type(8))) short short8;
typedef __attribute__((ext_vector_type(4))) float f32x4;

__device__ __forceinline__ u16 f2bf(float f) {
    u32 t; __builtin_memcpy(&t, &f, 4);
    u32 r = (t + 0x7FFFu + ((t >> 16) & 1u)) >> 16;
    return (u16)r;
}

__device__ __forceinline__ float waveReduceSum(float v) {
#pragma unroll
    for (int o = 32; o > 0; o >>= 1) v += __shfl_down(v, o);
    return v;
}

// block-wide reduce of 4 values across 16 waves (1024 threads)
__device__ __forceinline__ float4 blockReduce4w(float4 v, float4* red4, bool ismax) {
#pragma unroll
    for (int o = 32; o > 0; o >>= 1) {
        float4 t;
        t.x = __shfl_down(v.x, o); t.y = __shfl_down(v.y, o);
        t.z = __shfl_down(v.z, o); t.w = __shfl_down(v.w, o);
        if (ismax) {
            v.x = fmaxf(v.x, t.x); v.y = fmaxf(v.y, t.y);
            v.z = fmaxf(v.z, t.z); v.w = fmaxf(v.w, t.w);
        } else {
            v.x += t.x; v.y += t.y; v.z += t.z; v.w += t.w;
        }
    }
    int wid = threadIdx.x >> 6;
    __syncthreads();
    if ((threadIdx.x & 63) == 0) red4[wid] = v;
    __syncthreads();
    float4 r = red4[0];
#pragma unroll
    for (int w = 1; w < 16; ++w) {
        float4 u = red4[w];
        if (ismax) {
            r.x = fmaxf(r.x, u.x); r.y = fmaxf(r.y, u.y);
            r.z = fmaxf(r.z, u.z); r.w = fmaxf(r.w, u.w);
        } else {
            r.x += u.x; r.y += u.y; r.z += u.z; r.w += u.w;
        }
    }
    return r;
}

// ---------------- K0: convert x/Wq/Wk/Wv to bf16 AND transpose Wo ----------------
__global__ __launch_bounds__(256) void prep_kernel(
    const float* __restrict__ x, const float* __restrict__ Wq,
    const float* __restrict__ Wk, const float* __restrict__ Wv,
    const float* __restrict__ Wo,
    u16* __restrict__ xb, u16* __restrict__ Wb, float* __restrict__ Wot)
{
    const int blk = blockIdx.x;
    if (blk < 2816) {
        int t = blk * 256 + threadIdx.x;
        if (t < 524288) {
            xb[t] = f2bf(x[t]);
        } else {
            int u = t - 524288;
            const float* src = (u < 65536) ? Wq : (u < 131072) ? Wk : Wv;
            Wb[u] = f2bf(src[u & 65535]);
        }
    } else {
        __shared__ float t[32][33];
        const int t2 = blk - 2816;        // 0..63
        const int bx = t2 & 7, by = t2 >> 3;
        const int tx = threadIdx.x & 31, ty = threadIdx.x >> 5;
#pragma unroll
        for (int k = 0; k < 4; ++k)
            t[ty + 8 * k][tx] = Wo[(by * 32 + ty + 8 * k) * 256 + bx * 32 + tx];
        __syncthreads();
#pragma unroll
        for (int k = 0; k < 4; ++k)
            Wot[(bx * 32 + ty + 8 * k) * 256 + by * 32 + tx] = t[tx][ty + 8 * k];
    }
}

// ---------------- K1: q/k/v projections via bf16 MFMA ----------------
__global__ __launch_bounds__(256) void qkv_mfma(
    const u16* __restrict__ xb, const u16* __restrict__ Wb,
    const float* __restrict__ bq, const float* __restrict__ bk, const float* __restrict__ bv,
    float* __restrict__ q, float* __restrict__ k_t, float* __restrict__ v)
{
    const int lane = threadIdx.x & 63, wave = threadIdx.x >> 6;
    const int r0 = blockIdx.x * 64 + wave * 16;
    const int out0 = blockIdx.y * 16;
    const int which = blockIdx.y >> 4;
    const float* bia = (which == 0) ? bq : (which == 1) ? bk : bv;

    const int m = lane & 15, koff = (lane >> 4) * 8;
    const u16* Ap = xb + (size_t)(r0 + m) * 256 + koff;
    const u16* Bp = Wb + (size_t)(out0 + m) * 256 + koff;

    f32x4 acc = {0.f, 0.f, 0.f, 0.f};
#pragma unroll
    for (int kb = 0; kb < 8; ++kb) {
        short8 a  = *(const short8*)(Ap + kb * 32);
        short8 bf = *(const short8*)(Bp + kb * 32);
        acc = __builtin_amdgcn_mfma_f32_16x16x32_bf16(a, bf, acc, 0, 0, 0);
    }

    const int oc = (out0 + m) & 255;
    const float bias = bia[oc];
    const int rbase = r0 + (lane >> 4) * 4;
#pragma unroll
    for (int reg = 0; reg < 4; ++reg) {
        int R = rbase + reg;
        float val = acc[reg] + bias;
        if (which == 1)      k_t[((size_t)(R >> 9) * 256 + oc) * 512 + (R & 511)] = val;
        else if (which == 0) q[(size_t)R * 256 + oc] = val;
        else                 v[(size_t)R * 256 + oc] = val;
    }
}

// ---------------- K2: fused attention, TI=4 rows, 1024 threads ----------------
__global__ __launch_bounds__(1024, 8) void fused_kernel(
    const float* __restrict__ x, const float* __restrict__ area, const float* __restrict__ co,
    const float* __restrict__ We1, const float* __restrict__ be1,
    const float* __restrict__ We2, const float* __restrict__ be2,
    const float* __restrict__ Wot, const float* __restrict__ bo,
    const float* __restrict__ g_ot, const float* __restrict__ b_ot,
    const float* __restrict__ g1, const float* __restrict__ b1,
    const float* __restrict__ g2, const float* __restrict__ b2,
    const float* __restrict__ q, const float* __restrict__ k_t, const float* __restrict__ v,
    float* __restrict__ out)
{
    const int tid = threadIdx.x;
    const int b = blockIdx.x >> 7;
    const int i0 = (blockIdx.x & 127) << 2;
    const int lane = tid & 63, w = tid >> 6;
    const int tio = tid >> 8, ho = tid & 255;   // owner mapping (ti, h)

    __shared__ float ts[1024], ea[1024], eb[1024];     // raw gate tables / PV-Wo partials
    __shared__ float ts2[1024], ea2[1024], eb2[1024];  // sorted + scanned gate tables
    __shared__ float srow[2048];                       // QK partials -> probs -> y1
    __shared__ float4 red4[16];
    __shared__ float redA[16], redB[16];

    const float be2f = be2[0];

    // ---- phase 1: gate build, one hinge per thread (ti=tio, h=ho) ----
    float es_v, eb_v;
    {
        const float w10 = We1[2 * ho], w11 = We1[2 * ho + 1];
        const float w2v = We2[ho], be1v = be1[ho];
        const float a = area[b * NN + i0 + tio];
        float al = fmaf(a, w10, be1v);
        float s = w11 * w2v, bb = al * w2v;
        float t = 3e38f; es_v = 0.f; eb_v = 0.f;
        float baS = 0.f, baB = 0.f;
        if (w11 == 0.f) {
            if (al > 0.f) baB = bb;
        } else {
            float tt = -al / w11;
            if (w11 > 0.f) {
                if (tt <= 0.f)      { baS = s; baB = bb; }
                else if (tt < 1.f)  { t = tt; es_v = s; eb_v = bb; }
            } else {
                if (tt >= 1.f)      { baS = s; baB = bb; }
                else if (tt > 0.f)  { t = tt; es_v = -s; eb_v = -bb; baS = s; baB = bb; }
            }
        }
        ts[tid] = t;
        // per-ti base reduce: wave w has uniform ti = w>>2
        float sS = waveReduceSum(baS);
        float sB = waveReduceSum(baB);
        if (lane == 0) { redA[w] = sS; redB[w] = sB; }
        __syncthreads();
    }

    // ---- phase 2: rank sort (key ts, tie-break by h), wave-uniform broadcasts ----
    {
        const float tm = ts[tid];
        const float* tsb = &ts[tid & 768];
        int cnt = 0;
#pragma unroll 8
        for (int hp = 0; hp < 256; ++hp) {
            float tp = tsb[hp];
            cnt += (tp < tm) || (tp == tm && hp < ho);
        }
        int dsti = (tid & 768) + cnt;
        ts2[dsti] = tm; ea2[dsti] = es_v; eb2[dsti] = eb_v;
        __syncthreads();
    }

    // ---- phase 3: inclusive scan of (ea2, eb2), ping-pong with (ea, eb) ----
    {
        float* sa = ea2; float* sb = eb2; float* da = ea; float* db = eb;
        const int col = ho, base = tid & 768;
        for (int off = 1; off < 256; off <<= 1) {
            float va = sa[base + col], vb = sb[base + col];
            if (col >= off) { va += sa[base + col - off]; vb += sb[base + col - off]; }
            da[base + col] = va; db[base + col] = vb;
            __syncthreads();
            float* tmp = sa; sa = da; da = tmp;
            tmp = sb; sb = db; db = tmp;
        }
        // 8 stages -> final scanned values land back in ea2/eb2; keys in ts2
    }

    // ---- phase 4: QK dot, j = tid&511, h-half = tid>>9 ----
    const int j = tid & 511, hh = tid >> 9;
    float dotv[TI] = {0.f, 0.f, 0.f, 0.f};
    {
        const float* kt = k_t + (size_t)b * NH * NN + j;
        const float* qb_ = q + (size_t)(b * NN + i0) * NH;
        for (int h = hh * 128; h < hh * 128 + 128; h += 4) {
            float k0 = kt[(size_t)(h + 0) * 512];
            float k1 = kt[(size_t)(h + 1) * 512];
            float k2c = kt[(size_t)(h + 2) * 512];
            float k3 = kt[(size_t)(h + 3) * 512];
#pragma unroll
            for (int ti = 0; ti < TI; ++ti) {
                float4 qv = *(const float4*)&qb_[ti * 256 + h];  // wave-uniform -> s_load
                dotv[ti] += qv.x * k0 + qv.y * k1 + qv.z * k2c + qv.w * k3;
            }
        }
        if (hh == 1) {
#pragma unroll
            for (int ti = 0; ti < TI; ++ti) srow[ti * 512 + j] = dotv[ti];
        }
        __syncthreads();
        if (hh == 0) {
#pragma unroll
            for (int ti = 0; ti < TI; ++ti) dotv[ti] += srow[ti * 512 + j];
        }
    }

    // ---- phase 5: gate apply + softmax ----
    {
        float sA[TI] = {-3e38f, -3e38f, -3e38f, -3e38f};
        if (hh == 0) {
#pragma unroll
            for (int ti = 0; ti < TI; ++ti) {
                float c = co[(size_t)(i0 + ti) * NN + j];
                int r = 0;
                const float* tz = &ts2[ti * 256];
#pragma unroll
                for (int st = 128; st; st >>= 1)
                    if (tz[r + st - 1] <= c) r += st;
                float bS = redA[ti * 4] + redA[ti * 4 + 1] + redA[ti * 4 + 2] + redA[ti * 4 + 3];
                float bB = redB[ti * 4] + redB[ti * 4 + 1] + redB[ti * 4 + 2] + redB[ti * 4 + 3];
                float S = bS + (r ? ea2[ti * 256 + r - 1] : 0.f);
                float B = bB + (r ? eb2[ti * 256 + r - 1] : 0.f);
                float e = fmaf(c, S, B) + be2f;
                float ew = 1.f / (1.f + __expf(-e));
                sA[ti] = dotv[ti] * 0.0625f * ew;
            }
        }
        float4 m4 = make_float4(sA[0], sA[1], sA[2], sA[3]);
        m4 = blockReduce4w(m4, red4, true);
        float eA[TI];
        float4 s4;
#pragma unroll
        for (int ti = 0; ti < TI; ++ti) {
            eA[ti] = (hh == 0) ? __expf(sA[ti] - ((const float*)&m4)[ti]) : 0.f;
            ((float*)&s4)[ti] = eA[ti];
        }
        s4 = blockReduce4w(s4, red4, false);
        if (hh == 0) {
#pragma unroll
            for (int ti = 0; ti < TI; ++ti)
                srow[ti * 512 + j] = eA[ti] * (1.f / ((const float*)&s4)[ti]);
        }
        __syncthreads();
    }

    // ---- phase 6: PV, h = tid&255, j-quarter = tid>>8 ----
    float acc1;
    {
        const int qtr = tid >> 8;
        float accv[TI] = {0.f, 0.f, 0.f, 0.f};
        const float* vp = v + (size_t)b * NN * NH + ho;
        for (int j4 = qtr * 32; j4 < qtr * 32 + 32; ++j4) {
            const int jj = 4 * j4;
            float v0 = vp[(size_t)(jj + 0) * NH];
            float v1 = vp[(size_t)(jj + 1) * NH];
            float v2 = vp[(size_t)(jj + 2) * NH];
            float v3 = vp[(size_t)(jj + 3) * NH];
#pragma unroll
            for (int ti = 0; ti < TI; ++ti) {
                float4 p4 = *(const float4*)&srow[ti * 512 + jj];  // wave-uniform
                accv[ti] += p4.x * v0 + p4.y * v1 + p4.z * v2 + p4.w * v3;
            }
        }
        float* pq = (qtr == 0) ? ts2 : (qtr == 1) ? ts : (qtr == 2) ? ea : eb;
#pragma unroll
        for (int ti = 0; ti < TI; ++ti) pq[ti * 256 + ho] = accv[ti];
        __syncthreads();
        acc1 = ts2[tid] + ts[tid] + ea[tid] + eb[tid];  // owner (tio, ho)
    }

    // ---- phase 7: LN1 -> y1 in srow[0..1023] ----
    {
        float s = waveReduceSum(acc1);
        if (lane == 0) redA[w] = s;
        __syncthreads();
        float mean = (redA[tio * 4] + redA[tio * 4 + 1] + redA[tio * 4 + 2] + redA[tio * 4 + 3]) * (1.f / 256.f);
        float dd = acc1 - mean;
        float s2 = waveReduceSum(dd * dd);
        if (lane == 0) redB[w] = s2;
        __syncthreads();
        float var = (redB[tio * 4] + redB[tio * 4 + 1] + redB[tio * 4 + 2] + redB[tio * 4 + 3]) * (1.f / 256.f);
        srow[tid] = dd * rsqrtf(var + 1e-5f) * g1[ho] + b1[ho];
        __syncthreads();
    }

    // ---- phase 8: Wo GEMV, o = tid&255, d-quarter = tid>>8 ----
    float acc2o;
    {
        const int qtr = tid >> 8;
        float acc2[TI] = {0.f, 0.f, 0.f, 0.f};
        for (int d4 = qtr * 16; d4 < qtr * 16 + 16; ++d4) {
            const int d = 4 * d4;
            float w0 = Wot[(size_t)(d + 0) * 256 + ho];
            float w1 = Wot[(size_t)(d + 1) * 256 + ho];
            float w2c = Wot[(size_t)(d + 2) * 256 + ho];
            float w3 = Wot[(size_t)(d + 3) * 256 + ho];
#pragma unroll
            for (int ti = 0; ti < TI; ++ti) {
                float4 y4 = *(const float4*)&srow[ti * 256 + d];  // wave-uniform
                acc2[ti] += y4.x * w0 + y4.y * w1 + y4.z * w2c + y4.w * w3;
            }
        }
        float* pq = (qtr == 0) ? ts2 : (qtr == 1) ? ts : (qtr == 2) ? ea : eb;
#pragma unroll
        for (int ti = 0; ti < TI; ++ti) pq[ti * 256 + ho] = acc2[ti];
        __syncthreads();
        acc2o = ts2[tid] + ts[tid] + ea[tid] + eb[tid] + bo[ho];
    }

    // ---- phase 9: LN(g_ot, b_ot) + relu ----
    float z;
    {
        float s = waveReduceSum(acc2o);
        if (lane == 0) redA[w] = s;
        __syncthreads();
        float mean = (redA[tio * 4] + redA[tio * 4 + 1] + redA[tio * 4 + 2] + redA[tio * 4 + 3]) * (1.f / 256.f);
        float dd = acc2o - mean;
        float s2 = waveReduceSum(dd * dd);
        if (lane == 0) redB[w] = s2;
        __syncthreads();
        float var = (redB[tio * 4] + redB[tio * 4 + 1] + redB[tio * 4 + 2] + redB[tio * 4 + 3]) * (1.f / 256.f);
        z = fmaxf(dd * rsqrtf(var + 1e-5f) * g_ot[ho] + b_ot[ho], 0.f);
    }

    // ---- phase 10: residual + LN2 + store ----
    {
        float tt = z + x[(size_t)(b * NN + i0 + tio) * ND + ho];
        float s = waveReduceSum(tt);
        if (lane == 0) redA[w] = s;
        __syncthreads();
        float mean = (redA[tio * 4] + redA[tio * 4 + 1] + redA[tio * 4 + 2] + redA[tio * 4 + 3]) * (1.f / 256.f);
        float dd = tt - mean;
        float s2 = waveReduceSum(dd * dd);
        if (lane == 0) redB[w] = s2;
        __syncthreads();
        float var = (redB[tio * 4] + redB[tio * 4 + 1] + redB[tio * 4 + 2] + redB[tio * 4 + 3]) * (1.f / 256.f);
        float o = dd * rsqrtf(var + 1e-5f) * g2[ho] + b2[ho];
        out[(size_t)(b * NN + i0 + tio) * NH + ho] = o;
    }
}

extern "C" void kernel_launch(void* const* d_in, const int* in_sizes, int n_in,
                              void* d_out, int out_size, void* d_ws, size_t ws_size,
                              hipStream_t stream) {
    const float* x    = (const float*)d_in[0];
    const float* area = (const float*)d_in[1];
    const float* co   = (const float*)d_in[2];
    const float* Wq   = (const float*)d_in[3];
    const float* bq   = (const float*)d_in[4];
    const float* Wk   = (const float*)d_in[5];
    const float* bk   = (const float*)d_in[6];
    const float* Wv   = (const float*)d_in[7];
    const float* bv   = (const float*)d_in[8];
    const float* We1  = (const float*)d_in[9];
    const float* be1  = (const float*)d_in[10];
    const float* We2  = (const float*)d_in[11];
    const float* be2  = (const float*)d_in[12];
    const float* Wo   = (const float*)d_in[13];
    const float* bo   = (const float*)d_in[14];
    const float* g_ot = (const float*)d_in[15];
    const float* b_ot = (const float*)d_in[16];
    const float* g1   = (const float*)d_in[17];
    const float* b1   = (const float*)d_in[18];
    const float* g2   = (const float*)d_in[19];
    const float* b2   = (const float*)d_in[20];

    float* q   = (float*)d_ws;                         // 2 MB
    float* k_t = q + (size_t)NB * NN * NH;             // 2 MB
    float* v   = k_t + (size_t)NB * NN * NH;           // 2 MB
    float* Wot = v + (size_t)NB * NN * NH;             // 256 KB
    u16*   xb  = (u16*)(Wot + 256 * 256);              // 1 MB
    u16*   Wb  = xb + (size_t)NB * NN * ND;            // 384 KB

    prep_kernel<<<2880, 256, 0, stream>>>(x, Wq, Wk, Wv, Wo, xb, Wb, Wot);
    qkv_mfma<<<dim3(32, 48), 256, 0, stream>>>(xb, Wb, bq, bk, bv, q, k_t, v);
    fused_kernel<<<NB * NN / TI, 1024, 0, stream>>>(x, area, co, We1, be1, We2, be2, Wot, bo,
                                                    g_ot, b_ot, g1, b1, g2, b2, q, k_t, v,
                                                    (float*)d_out);
}

// Round 8
// 172.032 us; speedup vs baseline: 1.1173x; 1.1173x over previous
//
#include <hip/hip_runtime.h>

typedef unsigned short u16;
typedef unsigned int u32;

#define NB 4
#define NN 512
#define ND 256
#define NH 256
#define TI 4

typedef __attribute__((ext_vector_type(8))) short short8;
typedef __attribute__((ext_vector_type(4))) float f32x4;

__device__ __forceinline__ short bf(float f) {
    u32 t; __builtin_memcpy(&t, &f, 4);
    u32 r = (t + 0x7FFFu + ((t >> 16) & 1u)) >> 16;
    return (short)(u16)r;
}

__device__ __forceinline__ float waveReduceSum(float v) {
#pragma unroll
    for (int o = 32; o > 0; o >>= 1) v += __shfl_down(v, o);
    return v;
}

// block-wide reduce of 4 values across 8 waves (512 threads)
__device__ __forceinline__ float4 blockReduce4(float4 v, float4* red4b, bool ismax) {
#pragma unroll
    for (int o = 32; o > 0; o >>= 1) {
        float4 t;
        t.x = __shfl_down(v.x, o); t.y = __shfl_down(v.y, o);
        t.z = __shfl_down(v.z, o); t.w = __shfl_down(v.w, o);
        if (ismax) {
            v.x = fmaxf(v.x, t.x); v.y = fmaxf(v.y, t.y);
            v.z = fmaxf(v.z, t.z); v.w = fmaxf(v.w, t.w);
        } else {
            v.x += t.x; v.y += t.y; v.z += t.z; v.w += t.w;
        }
    }
    int wid = threadIdx.x >> 6;
    __syncthreads();
    if ((threadIdx.x & 63) == 0) red4b[wid] = v;
    __syncthreads();
    float4 r = red4b[0];
#pragma unroll
    for (int w = 1; w < 8; ++w) {
        float4 u = red4b[w];
        if (ismax) {
            r.x = fmaxf(r.x, u.x); r.y = fmaxf(r.y, u.y);
            r.z = fmaxf(r.z, u.z); r.w = fmaxf(r.w, u.w);
        } else {
            r.x += u.x; r.y += u.y; r.z += u.z; r.w += u.w;
        }
    }
    return r;
}

// ---------------- K1: q/k/v projections via bf16 MFMA (inline cvt) + Wo^T ----------------
// grid (32, 49), 256 thr. y<48: MFMA jobs (y = out-tile, 3x16; x = 64-row tile, wave=16 rows).
// y==48: Wo transpose (block x handles two 32x32 tiles).
__global__ __launch_bounds__(256) void qkv_mfma(
    const float* __restrict__ x,
    const float* __restrict__ Wq, const float* __restrict__ bq,
    const float* __restrict__ Wk, const float* __restrict__ bk,
    const float* __restrict__ Wv, const float* __restrict__ bv,
    const float* __restrict__ Wo,
    float* __restrict__ q, float* __restrict__ k_t, float* __restrict__ v,
    float* __restrict__ Wot)
{
    const int tid = threadIdx.x;
    if (blockIdx.y == 48) {
        __shared__ float t[32][33];
        const int tx = tid & 31, ty = tid >> 5;
#pragma unroll
        for (int tt2 = 0; tt2 < 2; ++tt2) {
            const int tile = blockIdx.x * 2 + tt2;    // 0..63
            const int bx = tile & 7, by = tile >> 3;
            __syncthreads();
#pragma unroll
            for (int k = 0; k < 4; ++k)
                t[ty + 8 * k][tx] = Wo[(size_t)(by * 32 + ty + 8 * k) * 256 + bx * 32 + tx];
            __syncthreads();
#pragma unroll
            for (int k = 0; k < 4; ++k)
                Wot[(size_t)(bx * 32 + ty + 8 * k) * 256 + by * 32 + tx] = t[tx][ty + 8 * k];
        }
        return;
    }

    const int lane = tid & 63, wave = tid >> 6;
    const int r0 = blockIdx.x * 64 + wave * 16;
    const int out0 = blockIdx.y * 16;                  // 0..767
    const int which = blockIdx.y >> 4;
    const float* W   = (which == 0) ? Wq : (which == 1) ? Wk : Wv;
    const float* bia = (which == 0) ? bq : (which == 1) ? bk : bv;

    const int m = lane & 15, koff = (lane >> 4) * 8;
    const float* Ap = x + (size_t)(r0 + m) * 256 + koff;
    const float* Bp = W + (size_t)((out0 & 255) + m) * 256 + koff;

    f32x4 acc = {0.f, 0.f, 0.f, 0.f};
#pragma unroll
    for (int kb = 0; kb < 8; ++kb) {
        float4 a0 = *(const float4*)(Ap + kb * 32);
        float4 a1 = *(const float4*)(Ap + kb * 32 + 4);
        float4 b0 = *(const float4*)(Bp + kb * 32);
        float4 b1 = *(const float4*)(Bp + kb * 32 + 4);
        short8 af, bf8;
        af[0] = bf(a0.x); af[1] = bf(a0.y); af[2] = bf(a0.z); af[3] = bf(a0.w);
        af[4] = bf(a1.x); af[5] = bf(a1.y); af[6] = bf(a1.z); af[7] = bf(a1.w);
        bf8[0] = bf(b0.x); bf8[1] = bf(b0.y); bf8[2] = bf(b0.z); bf8[3] = bf(b0.w);
        bf8[4] = bf(b1.x); bf8[5] = bf(b1.y); bf8[6] = bf(b1.z); bf8[7] = bf(b1.w);
        acc = __builtin_amdgcn_mfma_f32_16x16x32_bf16(af, bf8, acc, 0, 0, 0);
    }

    const int oc = (out0 + m) & 255;          // D col = lane&15
    const float bias = bia[oc];
    const int rbase = r0 + (lane >> 4) * 4;   // D row = (lane>>4)*4 + reg
#pragma unroll
    for (int reg = 0; reg < 4; ++reg) {
        int R = rbase + reg;
        float val = acc[reg] + bias;
        if (which == 1)      k_t[((size_t)(R >> 9) * 256 + oc) * 512 + (R & 511)] = val;
        else if (which == 0) q[(size_t)R * 256 + oc] = val;
        else                 v[(size_t)R * 256 + oc] = val;
    }
}

// ---------------- K2: fused attention, TI=4 rows, 512 threads, histogram gate ----------------
__global__ __launch_bounds__(512) void fused_kernel(
    const float* __restrict__ x, const float* __restrict__ area, const float* __restrict__ co,
    const float* __restrict__ We1, const float* __restrict__ be1,
    const float* __restrict__ We2, const float* __restrict__ be2,
    const float* __restrict__ Wot, const float* __restrict__ bo,
    const float* __restrict__ g_ot, const float* __restrict__ b_ot,
    const float* __restrict__ g1, const float* __restrict__ b1,
    const float* __restrict__ g2, const float* __restrict__ b2,
    const float* __restrict__ q, const float* __restrict__ k_t, const float* __restrict__ v,
    float* __restrict__ out)
{
    const int tid = threadIdx.x;
    const int b = blockIdx.x >> 7;
    const int i0 = (blockIdx.x & 127) << 2;
    const int lane = tid & 63, w = tid >> 6;

    __shared__ float histS[1024], histB[1024], hist2S[1024], hist2B[1024];
    __shared__ float srow[2048];
    __shared__ float4 red4b[8];
    __shared__ float sBaseS[4], sBaseB[4], redA[8], redB[8];

    const float be2f = be2[0];

    // ---- gate: zero hist, scatter hinge deltas, reduce always-active bases ----
    histS[tid] = 0.f; histS[tid + 512] = 0.f;
    histB[tid] = 0.f; histB[tid + 512] = 0.f;
    __syncthreads();
    {
        const int s = tid >> 7, h0 = tid & 127;            // set s = w>>1 (wave-uniform)
        const float a = area[b * NN + i0 + s];
        float baS = 0.f, baB = 0.f;
#pragma unroll
        for (int k = 0; k < 2; ++k) {
            const int h = h0 + 128 * k;
            const float w10 = We1[2 * h], w11 = We1[2 * h + 1];
            const float w2v = We2[h], be1v = be1[h];
            const float al = fmaf(a, w10, be1v);
            const float sl = w11 * w2v, bb = al * w2v;
            if (w11 == 0.f) {
                if (al > 0.f) baB += bb;
            } else {
                float tt = -al / w11;
                if (w11 > 0.f) {
                    if (tt <= 0.f)      { baS += sl; baB += bb; }
                    else if (tt < 1.f) {
                        int u = (int)(tt * 256.f); u = u > 255 ? 255 : u;
                        atomicAdd(&histS[s * 256 + u], sl);
                        atomicAdd(&histB[s * 256 + u], bb);
                    }
                } else {
                    if (tt >= 1.f)      { baS += sl; baB += bb; }
                    else if (tt > 0.f) {
                        baS += sl; baB += bb;
                        int u = (int)(tt * 256.f); u = u > 255 ? 255 : u;
                        atomicAdd(&histS[s * 256 + u], -sl);
                        atomicAdd(&histB[s * 256 + u], -bb);
                    }
                }
            }
        }
        float rS = waveReduceSum(baS), rB = waveReduceSum(baB);
        if (lane == 0) { redA[w] = rS; redB[w] = rB; }
    }
    __syncthreads();
    if (tid < 4) {
        sBaseS[tid] = redA[2 * tid] + redA[2 * tid + 1];
        sBaseB[tid] = redB[2 * tid] + redB[2 * tid + 1];
    }

    // ---- inclusive scan over 256 buckets x 4 sets (8 stages, ping-pong) ----
    {
        float* sa = histS; float* sb = histB; float* da = hist2S; float* db = hist2B;
        const int col = tid & 255;
        const int s2 = (tid >> 8) * 2;   // this thread handles sets s2, s2+1
        for (int off = 1; off < 256; off <<= 1) {
            const int i1 = s2 * 256 + col, i2 = (s2 + 1) * 256 + col;
            float v1a = sa[i1], v1b = sb[i1], v2a = sa[i2], v2b = sb[i2];
            if (col >= off) {
                v1a += sa[i1 - off]; v1b += sb[i1 - off];
                v2a += sa[i2 - off]; v2b += sb[i2 - off];
            }
            da[i1] = v1a; db[i1] = v1b; da[i2] = v2a; db[i2] = v2b;
            __syncthreads();
            float* t = sa; sa = da; da = t;
            t = sb; sb = db; db = t;
        }
        // 8 stages -> scanned tables end in histS/histB
    }

    // ---- QK dot (j = tid) + gate + score ----
    float sA[TI];
    {
        const float* kt = k_t + (size_t)b * NH * NN + tid;
        const float* qb_ = q + (size_t)(b * NN + i0) * NH;
        float dot[TI] = {0.f, 0.f, 0.f, 0.f};
        for (int h = 0; h < 256; h += 4) {
            float k0 = kt[(size_t)(h + 0) * 512];
            float k1 = kt[(size_t)(h + 1) * 512];
            float k2 = kt[(size_t)(h + 2) * 512];
            float k3 = kt[(size_t)(h + 3) * 512];
#pragma unroll
            for (int ti = 0; ti < TI; ++ti) {
                float4 qv = *(const float4*)&qb_[ti * 256 + h];  // wave-uniform -> s_load
                dot[ti] += qv.x * k0 + qv.y * k1 + qv.z * k2 + qv.w * k3;
            }
        }
#pragma unroll
        for (int ti = 0; ti < TI; ++ti) {
            float c = co[(size_t)(i0 + ti) * NN + tid];
            int u = (int)(c * 256.f); u = u > 255 ? 255 : u;
            float S = sBaseS[ti] + histS[ti * 256 + u];
            float B = sBaseB[ti] + histB[ti * 256 + u];
            float e = fmaf(c, S, B) + be2f;
            float ew = 1.f / (1.f + __expf(-e));
            sA[ti] = dot[ti] * 0.0625f * ew;
        }
    }

    // ---- softmax over j ----
    {
        float4 m4 = make_float4(sA[0], sA[1], sA[2], sA[3]);
        m4 = blockReduce4(m4, red4b, true);
        float eA[TI];
        float4 s4;
#pragma unroll
        for (int ti = 0; ti < TI; ++ti) {
            eA[ti] = __expf(sA[ti] - ((const float*)&m4)[ti]);
            ((float*)&s4)[ti] = eA[ti];
        }
        s4 = blockReduce4(s4, red4b, false);
#pragma unroll
        for (int ti = 0; ti < TI; ++ti)
            srow[ti * 512 + tid] = eA[ti] * (1.f / ((const float*)&s4)[ti]);
        __syncthreads();
    }

    // ---- PV: h = tid&255, j-half = tid>>8; partials via hist2S ----
    const int hP = tid & 255, half = tid >> 8;
    float accv[TI] = {0.f, 0.f, 0.f, 0.f};
    {
        const float* vp = v + (size_t)b * NN * NH + hP;
        for (int j4 = half * 64; j4 < half * 64 + 64; ++j4) {
            const int jj = 4 * j4;
            float v0 = vp[(size_t)(jj + 0) * NH];
            float v1 = vp[(size_t)(jj + 1) * NH];
            float v2 = vp[(size_t)(jj + 2) * NH];
            float v3 = vp[(size_t)(jj + 3) * NH];
#pragma unroll
            for (int ti = 0; ti < TI; ++ti) {
                float4 p4 = *(const float4*)&srow[ti * 512 + jj];  // wave-uniform
                accv[ti] += p4.x * v0 + p4.y * v1 + p4.z * v2 + p4.w * v3;
            }
        }
        if (half == 1) {
#pragma unroll
            for (int ti = 0; ti < TI; ++ti) hist2S[ti * 256 + hP] = accv[ti];
        }
        __syncthreads();
        if (half == 0) {
#pragma unroll
            for (int ti = 0; ti < TI; ++ti) accv[ti] += hist2S[ti * 256 + hP];
        }
    }

    // ---- LN1 -> y1 in srow[0..1023] ----
    float4 t4;
    float dd[TI];
#pragma unroll
    for (int ti = 0; ti < TI; ++ti) ((float*)&t4)[ti] = (half == 0) ? accv[ti] : 0.f;
    float4 mean4 = blockReduce4(t4, red4b, false);
#pragma unroll
    for (int ti = 0; ti < TI; ++ti) {
        dd[ti] = (half == 0) ? accv[ti] - ((const float*)&mean4)[ti] * (1.f / 256.f) : 0.f;
        ((float*)&t4)[ti] = dd[ti] * dd[ti];
    }
    float4 var4 = blockReduce4(t4, red4b, false);
    if (half == 0) {
        const float g1v = g1[hP], b1v = b1[hP];
#pragma unroll
        for (int ti = 0; ti < TI; ++ti)
            srow[ti * 256 + hP] = dd[ti] * rsqrtf(((const float*)&var4)[ti] * (1.f / 256.f) + 1e-5f) * g1v + b1v;
    }
    __syncthreads();

    // ---- Wo GEMV: o = tid&255, d-half = tid>>8; partials via histS ----
    float acc2[TI] = {0.f, 0.f, 0.f, 0.f};
    {
        for (int d4 = half * 32; d4 < half * 32 + 32; ++d4) {
            const int d = 4 * d4;
            float w0 = Wot[(size_t)(d + 0) * 256 + hP];
            float w1 = Wot[(size_t)(d + 1) * 256 + hP];
            float w2c = Wot[(size_t)(d + 2) * 256 + hP];
            float w3 = Wot[(size_t)(d + 3) * 256 + hP];
#pragma unroll
            for (int ti = 0; ti < TI; ++ti) {
                float4 y4 = *(const float4*)&srow[ti * 256 + d];  // wave-uniform
                acc2[ti] += y4.x * w0 + y4.y * w1 + y4.z * w2c + y4.w * w3;
            }
        }
        if (half == 1) {
#pragma unroll
            for (int ti = 0; ti < TI; ++ti) histS[ti * 256 + hP] = acc2[ti];
        }
        __syncthreads();
        if (half == 0) {
            const float bov = bo[hP];
#pragma unroll
            for (int ti = 0; ti < TI; ++ti) acc2[ti] += histS[ti * 256 + hP] + bov;
        }
    }

    // ---- LN(g_ot, b_ot) + relu ----
#pragma unroll
    for (int ti = 0; ti < TI; ++ti) ((float*)&t4)[ti] = (half == 0) ? acc2[ti] : 0.f;
    mean4 = blockReduce4(t4, red4b, false);
#pragma unroll
    for (int ti = 0; ti < TI; ++ti) {
        dd[ti] = (half == 0) ? acc2[ti] - ((const float*)&mean4)[ti] * (1.f / 256.f) : 0.f;
        ((float*)&t4)[ti] = dd[ti] * dd[ti];
    }
    var4 = blockReduce4(t4, red4b, false);
    float z[TI];
    const float gotv = (half == 0) ? g_ot[hP] : 0.f;
    const float botv = (half == 0) ? b_ot[hP] : 0.f;
#pragma unroll
    for (int ti = 0; ti < TI; ++ti)
        z[ti] = fmaxf(dd[ti] * rsqrtf(((const float*)&var4)[ti] * (1.f / 256.f) + 1e-5f) * gotv + botv, 0.f);

    // ---- residual + LN2 + store ----
    float tt[TI];
#pragma unroll
    for (int ti = 0; ti < TI; ++ti) {
        tt[ti] = (half == 0) ? z[ti] + x[(size_t)(b * NN + i0 + ti) * ND + hP] : 0.f;
        ((float*)&t4)[ti] = tt[ti];
    }
    mean4 = blockReduce4(t4, red4b, false);
#pragma unroll
    for (int ti = 0; ti < TI; ++ti) {
        dd[ti] = (half == 0) ? tt[ti] - ((const float*)&mean4)[ti] * (1.f / 256.f) : 0.f;
        ((float*)&t4)[ti] = dd[ti] * dd[ti];
    }
    var4 = blockReduce4(t4, red4b, false);
    if (half == 0) {
        const float g2v = g2[hP], b2v = b2[hP];
#pragma unroll
        for (int ti = 0; ti < TI; ++ti) {
            float o = dd[ti] * rsqrtf(((const float*)&var4)[ti] * (1.f / 256.f) + 1e-5f) * g2v + b2v;
            out[(size_t)(b * NN + i0 + ti) * NH + hP] = o;
        }
    }
}

extern "C" void kernel_launch(void* const* d_in, const int* in_sizes, int n_in,
                              void* d_out, int out_size, void* d_ws, size_t ws_size,
                              hipStream_t stream) {
    const float* x    = (const float*)d_in[0];
    const float* area = (const float*)d_in[1];
    const float* co   = (const float*)d_in[2];
    const float* Wq   = (const float*)d_in[3];
    const float* bq   = (const float*)d_in[4];
    const float* Wk   = (const float*)d_in[5];
    const float* bk   = (const float*)d_in[6];
    const float* Wv   = (const float*)d_in[7];
    const float* bv   = (const float*)d_in[8];
    const float* We1  = (const float*)d_in[9];
    const float* be1  = (const float*)d_in[10];
    const float* We2  = (const float*)d_in[11];
    const float* be2  = (const float*)d_in[12];
    const float* Wo   = (const float*)d_in[13];
    const float* bo   = (const float*)d_in[14];
    const float* g_ot = (const float*)d_in[15];
    const float* b_ot = (const float*)d_in[16];
    const float* g1   = (const float*)d_in[17];
    const float* b1   = (const float*)d_in[18];
    const float* g2   = (const float*)d_in[19];
    const float* b2   = (const float*)d_in[20];

    float* q   = (float*)d_ws;                         // 2 MB
    float* k_t = q + (size_t)NB * NN * NH;             // 2 MB
    float* v   = k_t + (size_t)NB * NN * NH;           // 2 MB
    float* Wot = v + (size_t)NB * NN * NH;             // 256 KB

    qkv_mfma<<<dim3(32, 49), 256, 0, stream>>>(x, Wq, bq, Wk, bk, Wv, bv, Wo,
                                               q, k_t, v, Wot);
    fused_kernel<<<NB * NN / TI, 512, 0, stream>>>(x, area, co, We1, be1, We2, be2, Wot, bo,
                                                   g_ot, b_ot, g1, b1, g2, b2, q, k_t, v,
                                                   (float*)d_out);
}

// Round 9
// 168.062 us; speedup vs baseline: 1.1437x; 1.0236x over previous
//
#include <hip/hip_runtime.h>

typedef unsigned short u16;
typedef unsigned int u32;

#define NB 4
#define NN 512
#define ND 256
#define NH 256
#define TI 4

typedef __attribute__((ext_vector_type(8))) short short8;
typedef __attribute__((ext_vector_type(4))) float f32x4;

__device__ __forceinline__ short bf(float f) {
    u32 t; __builtin_memcpy(&t, &f, 4);
    u32 r = (t + 0x7FFFu + ((t >> 16) & 1u)) >> 16;
    return (short)(u16)r;
}
__device__ __forceinline__ float blo(u32 u) {
    u32 t = u << 16; float f; __builtin_memcpy(&f, &t, 4); return f;
}
__device__ __forceinline__ float bhi(u32 u) {
    u32 t = u & 0xFFFF0000u; float f; __builtin_memcpy(&f, &t, 4); return f;
}

__device__ __forceinline__ float waveReduceSum(float v) {
#pragma unroll
    for (int o = 32; o > 0; o >>= 1) v += __shfl_down(v, o);
    return v;
}

// block-wide reduce of 4 values across 8 waves (512 threads)
__device__ __forceinline__ float4 blockReduce4(float4 v, float4* red4b, bool ismax) {
#pragma unroll
    for (int o = 32; o > 0; o >>= 1) {
        float4 t;
        t.x = __shfl_down(v.x, o); t.y = __shfl_down(v.y, o);
        t.z = __shfl_down(v.z, o); t.w = __shfl_down(v.w, o);
        if (ismax) {
            v.x = fmaxf(v.x, t.x); v.y = fmaxf(v.y, t.y);
            v.z = fmaxf(v.z, t.z); v.w = fmaxf(v.w, t.w);
        } else {
            v.x += t.x; v.y += t.y; v.z += t.z; v.w += t.w;
        }
    }
    int wid = threadIdx.x >> 6;
    __syncthreads();
    if ((threadIdx.x & 63) == 0) red4b[wid] = v;
    __syncthreads();
    float4 r = red4b[0];
#pragma unroll
    for (int w = 1; w < 8; ++w) {
        float4 u = red4b[w];
        if (ismax) {
            r.x = fmaxf(r.x, u.x); r.y = fmaxf(r.y, u.y);
            r.z = fmaxf(r.z, u.z); r.w = fmaxf(r.w, u.w);
        } else {
            r.x += u.x; r.y += u.y; r.z += u.z; r.w += u.w;
        }
    }
    return r;
}

// ---------------- K1: q/k/v projections via bf16 MFMA (inline cvt) + Wo^T ----------------
// grid (32, 49), 256 thr. y<48: MFMA jobs. y==48: Wo transpose -> packed bf16.
// q fp32 [row][h]; k -> kp u16 [b][h>>1][j][h&1]; v -> vp u16 [row][h]; Wo^T -> wop u16 [d>>1][o][d&1].
__global__ __launch_bounds__(256) void qkv_mfma(
    const float* __restrict__ x,
    const float* __restrict__ Wq, const float* __restrict__ bq,
    const float* __restrict__ Wk, const float* __restrict__ bk,
    const float* __restrict__ Wv, const float* __restrict__ bv,
    const float* __restrict__ Wo,
    float* __restrict__ q, u16* __restrict__ kp, u16* __restrict__ vp,
    u16* __restrict__ wop)
{
    const int tid = threadIdx.x;
    if (blockIdx.y == 48) {
        __shared__ float t[32][33];
        const int tx = tid & 31, ty = tid >> 5;
#pragma unroll
        for (int tt2 = 0; tt2 < 2; ++tt2) {
            const int tile = blockIdx.x * 2 + tt2;    // 0..63
            const int bx = tile & 7, by = tile >> 3;
            __syncthreads();
#pragma unroll
            for (int k = 0; k < 4; ++k)
                t[ty + 8 * k][tx] = Wo[(size_t)(by * 32 + ty + 8 * k) * 256 + bx * 32 + tx];
            __syncthreads();
#pragma unroll
            for (int k = 0; k < 4; ++k) {
                const int d = bx * 32 + ty + 8 * k, o = by * 32 + tx;
                wop[(size_t)(d >> 1) * 512 + 2 * o + (d & 1)] = (u16)bf(t[tx][ty + 8 * k]);
            }
        }
        return;
    }

    const int lane = tid & 63, wave = tid >> 6;
    const int r0 = blockIdx.x * 64 + wave * 16;
    const int out0 = blockIdx.y * 16;                  // 0..767
    const int which = blockIdx.y >> 4;
    const float* W   = (which == 0) ? Wq : (which == 1) ? Wk : Wv;
    const float* bia = (which == 0) ? bq : (which == 1) ? bk : bv;

    const int m = lane & 15, koff = (lane >> 4) * 8;
    const float* Ap = x + (size_t)(r0 + m) * 256 + koff;
    const float* Bp = W + (size_t)((out0 & 255) + m) * 256 + koff;

    f32x4 acc = {0.f, 0.f, 0.f, 0.f};
#pragma unroll
    for (int kb = 0; kb < 8; ++kb) {
        float4 a0 = *(const float4*)(Ap + kb * 32);
        float4 a1 = *(const float4*)(Ap + kb * 32 + 4);
        float4 b0 = *(const float4*)(Bp + kb * 32);
        float4 b1 = *(const float4*)(Bp + kb * 32 + 4);
        short8 af, bf8;
        af[0] = bf(a0.x); af[1] = bf(a0.y); af[2] = bf(a0.z); af[3] = bf(a0.w);
        af[4] = bf(a1.x); af[5] = bf(a1.y); af[6] = bf(a1.z); af[7] = bf(a1.w);
        bf8[0] = bf(b0.x); bf8[1] = bf(b0.y); bf8[2] = bf(b0.z); bf8[3] = bf(b0.w);
        bf8[4] = bf(b1.x); bf8[5] = bf(b1.y); bf8[6] = bf(b1.z); bf8[7] = bf(b1.w);
        acc = __builtin_amdgcn_mfma_f32_16x16x32_bf16(af, bf8, acc, 0, 0, 0);
    }

    const int oc = (out0 + m) & 255;          // D col = lane&15
    const float bias = bia[oc];
    const int rbase = r0 + (lane >> 4) * 4;   // D row = (lane>>4)*4 + reg
#pragma unroll
    for (int reg = 0; reg < 4; ++reg) {
        int R = rbase + reg;
        float val = acc[reg] + bias;
        if (which == 0) {
            q[(size_t)R * 256 + oc] = val;
        } else if (which == 1) {
            const int b_ = R >> 9, n = R & 511;
            kp[((size_t)(b_ * 128 + (oc >> 1)) * 512 + n) * 2 + (oc & 1)] = (u16)bf(val);
        } else {
            vp[(size_t)R * 256 + oc] = (u16)bf(val);
        }
    }
}

// ---------------- K2: fused attention, TI=4 rows, 512 threads, histogram gate ----------------
__global__ __launch_bounds__(512) void fused_kernel(
    const float* __restrict__ x, const float* __restrict__ area, const float* __restrict__ co,
    const float* __restrict__ We1, const float* __restrict__ be1,
    const float* __restrict__ We2, const float* __restrict__ be2,
    const u32* __restrict__ wop32, const float* __restrict__ bo,
    const float* __restrict__ g_ot, const float* __restrict__ b_ot,
    const float* __restrict__ g1, const float* __restrict__ b1,
    const float* __restrict__ g2, const float* __restrict__ b2,
    const float* __restrict__ q, const u32* __restrict__ kp32, const u32* __restrict__ vp32,
    float* __restrict__ out)
{
    const int tid = threadIdx.x;
    const int b = blockIdx.x >> 7;
    const int i0 = (blockIdx.x & 127) << 2;
    const int lane = tid & 63, w = tid >> 6;

    __shared__ float histS[1024], histB[1024], hist2S[1024], hist2B[1024];
    __shared__ float srow[2048];
    __shared__ float4 red4b[8];
    __shared__ float sBaseS[4], sBaseB[4], redA[8], redB[8];

    const float be2f = be2[0];

    // ---- gate: zero hist, scatter hinge deltas, reduce always-active bases ----
    histS[tid] = 0.f; histS[tid + 512] = 0.f;
    histB[tid] = 0.f; histB[tid + 512] = 0.f;
    __syncthreads();
    {
        const int s = tid >> 7, h0 = tid & 127;            // set s = w>>1 (wave-uniform)
        const float a = area[b * NN + i0 + s];
        float baS = 0.f, baB = 0.f;
#pragma unroll
        for (int k = 0; k < 2; ++k) {
            const int h = h0 + 128 * k;
            const float w10 = We1[2 * h], w11 = We1[2 * h + 1];
            const float w2v = We2[h], be1v = be1[h];
            const float al = fmaf(a, w10, be1v);
            const float sl = w11 * w2v, bb = al * w2v;
            if (w11 == 0.f) {
                if (al > 0.f) baB += bb;
            } else {
                float tt = -al / w11;
                if (w11 > 0.f) {
                    if (tt <= 0.f)      { baS += sl; baB += bb; }
                    else if (tt < 1.f) {
                        int u = (int)(tt * 256.f); u = u > 255 ? 255 : u;
                        atomicAdd(&histS[s * 256 + u], sl);
                        atomicAdd(&histB[s * 256 + u], bb);
                    }
                } else {
                    if (tt >= 1.f)      { baS += sl; baB += bb; }
                    else if (tt > 0.f) {
                        baS += sl; baB += bb;
                        int u = (int)(tt * 256.f); u = u > 255 ? 255 : u;
                        atomicAdd(&histS[s * 256 + u], -sl);
                        atomicAdd(&histB[s * 256 + u], -bb);
                    }
                }
            }
        }
        float rS = waveReduceSum(baS), rB = waveReduceSum(baB);
        if (lane == 0) { redA[w] = rS; redB[w] = rB; }
    }
    __syncthreads();
    if (tid < 4) {
        sBaseS[tid] = redA[2 * tid] + redA[2 * tid + 1];
        sBaseB[tid] = redB[2 * tid] + redB[2 * tid + 1];
    }

    // ---- inclusive scan over 256 buckets x 4 sets (8 stages, ping-pong) ----
    {
        float* sa = histS; float* sb = histB; float* da = hist2S; float* db = hist2B;
        const int col = tid & 255;
        const int s2 = (tid >> 8) * 2;   // this thread handles sets s2, s2+1
        for (int off = 1; off < 256; off <<= 1) {
            const int i1 = s2 * 256 + col, i2 = (s2 + 1) * 256 + col;
            float v1a = sa[i1], v1b = sb[i1], v2a = sa[i2], v2b = sb[i2];
            if (col >= off) {
                v1a += sa[i1 - off]; v1b += sb[i1 - off];
                v2a += sa[i2 - off]; v2b += sb[i2 - off];
            }
            da[i1] = v1a; db[i1] = v1b; da[i2] = v2a; db[i2] = v2b;
            __syncthreads();
            float* t = sa; sa = da; da = t;
            t = sb; sb = db; db = t;
        }
        // 8 stages (even) -> scanned tables end in histS/histB
    }

    // ---- QK dot (j = tid) + gate + score; k as packed bf16 pairs along h ----
    float sA[TI];
    {
        const u32* kt = kp32 + (size_t)b * 128 * 512 + tid;
        const float* qb_ = q + (size_t)(b * NN + i0) * NH;
        float dot[TI] = {0.f, 0.f, 0.f, 0.f};
        for (int h = 0; h < 256; h += 4) {   // 64 iters, 2 u32 loads each
            const int h2 = h >> 1;
            u32 ka = kt[(size_t)h2 * 512];
            u32 kb = kt[(size_t)(h2 + 1) * 512];
            float k0 = blo(ka), k1 = bhi(ka), k2 = blo(kb), k3 = bhi(kb);
#pragma unroll
            for (int ti = 0; ti < TI; ++ti) {
                float4 qv = *(const float4*)&qb_[ti * 256 + h];  // wave-uniform -> s_load
                dot[ti] += qv.x * k0 + qv.y * k1 + qv.z * k2 + qv.w * k3;
            }
        }
#pragma unroll
        for (int ti = 0; ti < TI; ++ti) {
            float c = co[(size_t)(i0 + ti) * NN + tid];
            int u = (int)(c * 256.f); u = u > 255 ? 255 : u;
            float S = sBaseS[ti] + histS[ti * 256 + u];
            float B = sBaseB[ti] + histB[ti * 256 + u];
            float e = fmaf(c, S, B) + be2f;
            float ew = 1.f / (1.f + __expf(-e));
            sA[ti] = dot[ti] * 0.0625f * ew;
        }
    }

    // ---- softmax over j ----
    {
        float4 m4 = make_float4(sA[0], sA[1], sA[2], sA[3]);
        m4 = blockReduce4(m4, red4b, true);
        float eA[TI];
        float4 s4;
#pragma unroll
        for (int ti = 0; ti < TI; ++ti) {
            eA[ti] = __expf(sA[ti] - ((const float*)&m4)[ti]);
            ((float*)&s4)[ti] = eA[ti];
        }
        s4 = blockReduce4(s4, red4b, false);
#pragma unroll
        for (int ti = 0; ti < TI; ++ti)
            srow[ti * 512 + tid] = eA[ti] * (1.f / ((const float*)&s4)[ti]);
        __syncthreads();
    }

    // ---- PV: thread = (h-pair h2, j-quarter qtr); v packed bf16 pairs along h ----
    {
        const int h2 = tid & 127, qtr = tid >> 7;
        float a0[TI] = {0.f, 0.f, 0.f, 0.f};   // h = 2*h2
        float a1[TI] = {0.f, 0.f, 0.f, 0.f};   // h = 2*h2+1
        const u32* vp_ = vp32 + (size_t)b * 512 * 128 + h2;
        const float4* s4p = (const float4*)srow;
        for (int j4 = qtr * 32; j4 < qtr * 32 + 32; ++j4) {
            const int jj = 4 * j4;
            u32 va = vp_[(size_t)(jj + 0) * 128];
            u32 vb = vp_[(size_t)(jj + 1) * 128];
            u32 vc = vp_[(size_t)(jj + 2) * 128];
            u32 vd = vp_[(size_t)(jj + 3) * 128];
            float la = blo(va), ha = bhi(va), lb = blo(vb), hb = bhi(vb);
            float lc = blo(vc), hc = bhi(vc), ld = blo(vd), hd = bhi(vd);
#pragma unroll
            for (int ti = 0; ti < TI; ++ti) {
                float4 p4 = s4p[ti * 128 + j4];  // wave-uniform LDS broadcast
                a0[ti] += p4.x * la + p4.y * lb + p4.z * lc + p4.w * ld;
                a1[ti] += p4.x * ha + p4.y * hb + p4.z * hc + p4.w * hd;
            }
        }
        float2* bq_ = (float2*)((qtr == 0) ? histS : (qtr == 1) ? histB : (qtr == 2) ? hist2S : hist2B);
#pragma unroll
        for (int ti = 0; ti < TI; ++ti) bq_[ti * 128 + h2] = make_float2(a0[ti], a1[ti]);
        __syncthreads();
    }

    const int hP = tid & 255, half = tid >> 8;
    float accv[TI] = {0.f, 0.f, 0.f, 0.f};
    if (half == 0) {
#pragma unroll
        for (int ti = 0; ti < TI; ++ti)
            accv[ti] = histS[ti * 256 + hP] + histB[ti * 256 + hP]
                     + hist2S[ti * 256 + hP] + hist2B[ti * 256 + hP];
    }

    // ---- LN1 -> y1 in srow[0..1023] ----
    float4 t4;
    float dd[TI];
#pragma unroll
    for (int ti = 0; ti < TI; ++ti) ((float*)&t4)[ti] = (half == 0) ? accv[ti] : 0.f;
    float4 mean4 = blockReduce4(t4, red4b, false);
#pragma unroll
    for (int ti = 0; ti < TI; ++ti) {
        dd[ti] = (half == 0) ? accv[ti] - ((const float*)&mean4)[ti] * (1.f / 256.f) : 0.f;
        ((float*)&t4)[ti] = dd[ti] * dd[ti];
    }
    float4 var4 = blockReduce4(t4, red4b, false);
    if (half == 0) {
        const float g1v = g1[hP], b1v = b1[hP];
#pragma unroll
        for (int ti = 0; ti < TI; ++ti)
            srow[ti * 256 + hP] = dd[ti] * rsqrtf(((const float*)&var4)[ti] * (1.f / 256.f) + 1e-5f) * g1v + b1v;
    }
    __syncthreads();

    // ---- Wo GEMV: o = tid&255, d-half = tid>>8; Wo^T packed bf16 pairs along d ----
    float acc2[TI] = {0.f, 0.f, 0.f, 0.f};
    {
        const u32* wp = wop32 + hP;
        const float4* y4p = (const float4*)srow;
        for (int d8 = half * 16; d8 < half * 16 + 16; ++d8) {   // d = 8*d8, 16 iters
            const int d2 = 4 * d8;
            u32 w01 = wp[(size_t)(d2 + 0) * 256];
            u32 w23 = wp[(size_t)(d2 + 1) * 256];
            u32 w45 = wp[(size_t)(d2 + 2) * 256];
            u32 w67 = wp[(size_t)(d2 + 3) * 256];
            float f0 = blo(w01), f1 = bhi(w01), f2 = blo(w23), f3 = bhi(w23);
            float f4 = blo(w45), f5 = bhi(w45), f6 = blo(w67), f7 = bhi(w67);
#pragma unroll
            for (int ti = 0; ti < TI; ++ti) {
                float4 ya = y4p[ti * 64 + 2 * d8];      // y1[ti*256 + 8*d8 .. +3]
                float4 yb = y4p[ti * 64 + 2 * d8 + 1];  // y1[ti*256 + 8*d8+4 .. +7]
                acc2[ti] += ya.x * f0 + ya.y * f1 + ya.z * f2 + ya.w * f3
                          + yb.x * f4 + yb.y * f5 + yb.z * f6 + yb.w * f7;
            }
        }
        if (half == 1) {
#pragma unroll
            for (int ti = 0; ti < TI; ++ti) histS[ti * 256 + hP] = acc2[ti];
        }
        __syncthreads();
        if (half == 0) {
            const float bov = bo[hP];
#pragma unroll
            for (int ti = 0; ti < TI; ++ti) acc2[ti] += histS[ti * 256 + hP] + bov;
        }
    }

    // ---- LN(g_ot, b_ot) + relu ----
#pragma unroll
    for (int ti = 0; ti < TI; ++ti) ((float*)&t4)[ti] = (half == 0) ? acc2[ti] : 0.f;
    mean4 = blockReduce4(t4, red4b, false);
#pragma unroll
    for (int ti = 0; ti < TI; ++ti) {
        dd[ti] = (half == 0) ? acc2[ti] - ((const float*)&mean4)[ti] * (1.f / 256.f) : 0.f;
        ((float*)&t4)[ti] = dd[ti] * dd[ti];
    }
    var4 = blockReduce4(t4, red4b, false);
    float z[TI];
    const float gotv = (half == 0) ? g_ot[hP] : 0.f;
    const float botv = (half == 0) ? b_ot[hP] : 0.f;
#pragma unroll
    for (int ti = 0; ti < TI; ++ti)
        z[ti] = fmaxf(dd[ti] * rsqrtf(((const float*)&var4)[ti] * (1.f / 256.f) + 1e-5f) * gotv + botv, 0.f);

    // ---- residual + LN2 + store ----
    float tt[TI];
#pragma unroll
    for (int ti = 0; ti < TI; ++ti) {
        tt[ti] = (half == 0) ? z[ti] + x[(size_t)(b * NN + i0 + ti) * ND + hP] : 0.f;
        ((float*)&t4)[ti] = tt[ti];
    }
    mean4 = blockReduce4(t4, red4b, false);
#pragma unroll
    for (int ti = 0; ti < TI; ++ti) {
        dd[ti] = (half == 0) ? tt[ti] - ((const float*)&mean4)[ti] * (1.f / 256.f) : 0.f;
        ((float*)&t4)[ti] = dd[ti] * dd[ti];
    }
    var4 = blockReduce4(t4, red4b, false);
    if (half == 0) {
        const float g2v = g2[hP], b2v = b2[hP];
#pragma unroll
        for (int ti = 0; ti < TI; ++ti) {
            float o = dd[ti] * rsqrtf(((const float*)&var4)[ti] * (1.f / 256.f) + 1e-5f) * g2v + b2v;
            out[(size_t)(b * NN + i0 + ti) * NH + hP] = o;
        }
    }
}

extern "C" void kernel_launch(void* const* d_in, const int* in_sizes, int n_in,
                              void* d_out, int out_size, void* d_ws, size_t ws_size,
                              hipStream_t stream) {
    const float* x    = (const float*)d_in[0];
    const float* area = (const float*)d_in[1];
    const float* co   = (const float*)d_in[2];
    const float* Wq   = (const float*)d_in[3];
    const float* bq   = (const float*)d_in[4];
    const float* Wk   = (const float*)d_in[5];
    const float* bk   = (const float*)d_in[6];
    const float* Wv   = (const float*)d_in[7];
    const float* bv   = (const float*)d_in[8];
    const float* We1  = (const float*)d_in[9];
    const float* be1  = (const float*)d_in[10];
    const float* We2  = (const float*)d_in[11];
    const float* be2  = (const float*)d_in[12];
    const float* Wo   = (const float*)d_in[13];
    const float* bo   = (const float*)d_in[14];
    const float* g_ot = (const float*)d_in[15];
    const float* b_ot = (const float*)d_in[16];
    const float* g1   = (const float*)d_in[17];
    const float* b1   = (const float*)d_in[18];
    const float* g2   = (const float*)d_in[19];
    const float* b2   = (const float*)d_in[20];

    float* q  = (float*)d_ws;                          // 2 MB
    u16*  kp  = (u16*)(q + (size_t)2048 * 256);        // 1 MB  [b][h>>1][j][h&1]
    u16*  vp  = kp + (size_t)4 * 128 * 512 * 2;        // 1 MB  [row][h]
    u16*  wop = vp + (size_t)2048 * 256;               // 128 KB [d>>1][o][d&1]

    qkv_mfma<<<dim3(32, 49), 256, 0, stream>>>(x, Wq, bq, Wk, bk, Wv, bv, Wo,
                                               q, kp, vp, wop);
    fused_kernel<<<NB * NN / TI, 512, 0, stream>>>(x, area, co, We1, be1, We2, be2,
                                                   (const u32*)wop, bo,
                                                   g_ot, b_ot, g1, b1, g2, b2,
                                                   q, (const u32*)kp, (const u32*)vp,
                                                   (float*)d_out);
}